// Round 2
// 416.417 us; speedup vs baseline: 1.0062x; 1.0062x over previous
//
#include <hip/hip_runtime.h>

#define Bdim 8
#define Tdim 2048
#define Cdim 1024
#define CHUNK 128
#define NCHUNK 16
#define BC (Bdim*Cdim)

typedef float floatx4 __attribute__((ext_vector_type(4)));
typedef _Float16 half8 __attribute__((ext_vector_type(8)));
typedef _Float16 half4v __attribute__((ext_vector_type(4)));

__device__ __forceinline__ void load16(const void* g, void* l) {
    __builtin_amdgcn_global_load_lds(
        (const __attribute__((address_space(1))) void*)g,
        (__attribute__((address_space(3))) void*)l, 16, 0, 0);
}

// ---------------- Kernel 1: embedding gather + shift row, fp32 -> f16 ----------------
__global__ __launch_bounds__(256) void embed_mix(const int* __restrict__ tokens,
                                                 const float* __restrict__ xx_init,
                                                 const float* __restrict__ emb,
                                                 _Float16* __restrict__ xe) {
    int row = blockIdx.x;              // 0 .. B*(T+1)-1
    int b = row / (Tdim + 1);
    int tt = row % (Tdim + 1);
    const float* src;
    if (tt == 0) src = xx_init + (size_t)b * Cdim;
    else         src = emb + (size_t)tokens[b * Tdim + tt - 1] * Cdim;
    int c0 = threadIdx.x * 4;
    float4 f = *reinterpret_cast<const float4*>(src + c0);
    half4v h;
    h[0] = (_Float16)f.x; h[1] = (_Float16)f.y; h[2] = (_Float16)f.z; h[3] = (_Float16)f.w;
    *reinterpret_cast<half4v*>(xe + (size_t)row * Cdim + c0) = h;
}

// ---------------- Kernel 1b: time-mix precompute, f16 in -> f16 out (x3) ----------------
__global__ __launch_bounds__(256) void mix3(const _Float16* __restrict__ xe,
                                            const float* __restrict__ tmk,
                                            const float* __restrict__ tmv,
                                            const float* __restrict__ tmr,
                                            _Float16* __restrict__ xk,
                                            _Float16* __restrict__ xv,
                                            _Float16* __restrict__ xr) {
    int row = blockIdx.x;              // b*T + t
    int b = row >> 11;
    int t = row & (Tdim - 1);
    const _Float16* cur = xe + ((size_t)(b * (Tdim + 1) + t + 1)) * Cdim;
    const _Float16* prv = cur - Cdim;
    int c = threadIdx.x * 4;
    half4v cu = *reinterpret_cast<const half4v*>(cur + c);
    half4v pv = *reinterpret_cast<const half4v*>(prv + c);
    float4 mk = *reinterpret_cast<const float4*>(tmk + c);
    float4 mv = *reinterpret_cast<const float4*>(tmv + c);
    float4 mr = *reinterpret_cast<const float4*>(tmr + c);
    half4v hk, hv, hr;
    float cf[4] = {(float)cu[0], (float)cu[1], (float)cu[2], (float)cu[3]};
    float pf[4] = {(float)pv[0], (float)pv[1], (float)pv[2], (float)pv[3]};
    float mkf[4] = {mk.x, mk.y, mk.z, mk.w};
    float mvf[4] = {mv.x, mv.y, mv.z, mv.w};
    float mrf[4] = {mr.x, mr.y, mr.z, mr.w};
    #pragma unroll
    for (int j = 0; j < 4; j++) {
        hk[j] = (_Float16)(mkf[j] * cf[j] + (1.0f - mkf[j]) * pf[j]);
        hv[j] = (_Float16)(mvf[j] * cf[j] + (1.0f - mvf[j]) * pf[j]);
        hr[j] = (_Float16)(mrf[j] * cf[j] + (1.0f - mrf[j]) * pf[j]);
    }
    size_t o = (size_t)row * Cdim + c;
    *reinterpret_cast<half4v*>(xk + o) = hk;
    *reinterpret_cast<half4v*>(xv + o) = hv;
    *reinterpret_cast<half4v*>(xr + o) = hr;
}

// ---------------- Kernel 1c: W fp32 -> f16 ----------------
__global__ __launch_bounds__(256) void wconv(const float* __restrict__ Wk,
                                             const float* __restrict__ Wv,
                                             const float* __restrict__ Wr,
                                             _Float16* __restrict__ Wh) {
    const float* W = blockIdx.y == 0 ? Wk : (blockIdx.y == 1 ? Wv : Wr);
    _Float16* dst = Wh + (size_t)blockIdx.y * Cdim * Cdim;
    int i = (blockIdx.x * 256 + threadIdx.x) * 4;
    float4 f = *reinterpret_cast<const float4*>(W + i);
    half4v h;
    h[0] = (_Float16)f.x; h[1] = (_Float16)f.y; h[2] = (_Float16)f.z; h[3] = (_Float16)f.w;
    *reinterpret_cast<half4v*>(dst + i) = h;
}

// ---------------- Kernel 2: deep-pipelined f16 GEMM (NT), 256x256 tile, BK=32 ----------------
// out[m,n] = sum_c X[m,c] * W[n,c];  which=2 gets sigmoid.
// 4 LDS buffers, stage 3 K-tiles ahead, counted s_waitcnt vmcnt(8) (never drain
// to 0 in main loop), 1 raw s_barrier per K-tile.  BK=32: each fragment read is
// a bijection onto one aligned 1KB LDS block -> conflict-free without swizzle,
// and global_load_lds destinations stay linear (m104 constraint).
__global__ __launch_bounds__(512, 2) void gemm_kvr(const _Float16* __restrict__ xk,
                                                   const _Float16* __restrict__ xv,
                                                   const _Float16* __restrict__ xr,
                                                   const _Float16* __restrict__ Wh,
                                                   _Float16* __restrict__ ko,
                                                   _Float16* __restrict__ vo,
                                                   _Float16* __restrict__ ro) {
    const int which = blockIdx.y;
    const _Float16* X = which == 0 ? xk : (which == 1 ? xv : xr);
    const _Float16* W = Wh + (size_t)which * Cdim * Cdim;
    _Float16* out     = which == 0 ? ko : (which == 1 ? vo : ro);

    // XCD-aware swizzle: all 4 n-tiles of one m-tile group on the same XCD
    const int lin = blockIdx.x;        // 0..255
    const int xcd = lin & 7;
    const int loc = lin >> 3;          // 0..31
    const int mt = xcd * 8 + (loc >> 2);   // 0..63
    const int nt = loc & 3;                // 0..3
    const int m0 = mt * 256;
    const int n0 = nt * 256;

    // 4 K-tile buffers: 4 * (16KB A + 16KB B) = 128 KB
    __shared__ _Float16 As[4 * 8192];
    __shared__ _Float16 Bs[4 * 8192];

    const int tid = threadIdx.x;
    const int lane = tid & 63;
    const int wave = tid >> 6;         // 0..7
    const int wm = (wave >> 2) * 128;  // 2 M-groups
    const int wn = (wave & 3) * 64;    // 4 N-groups
    const int lr = lane & 15;          // fragment row within 16
    const int lk = lane >> 4;          // fragment k-block 0..3

    const _Float16* Asrc = X + (size_t)m0 * Cdim;
    const _Float16* Bsrc = W + (size_t)n0 * Cdim;

    floatx4 acc[8][4] = {};

    // stage K-tile kt into buffer kt&3 (4 global_load_lds per thread)
    auto stage = [&](int kt) {
        const int p = kt & 3;
        const int k0 = kt * 32;
        #pragma unroll
        for (int i = 0; i < 2; i++) {
            int e = i * 512 + tid;         // 16B slot, 0..1023
            int r = e >> 2;                // tile row 0..255
            int s = e & 3;                 // 8-f16 col block 0..3
            load16(Asrc + (size_t)r * Cdim + k0 + s * 8, (char*)(As + p * 8192) + e * 16);
        }
        #pragma unroll
        for (int i = 0; i < 2; i++) {
            int e = i * 512 + tid;
            int r = e >> 2;
            int s = e & 3;
            load16(Bsrc + (size_t)r * Cdim + k0 + s * 8, (char*)(Bs + p * 8192) + e * 16);
        }
    };

    // ds_read fragments from buffer kt&3 and run 32 MFMAs
    auto compute = [&](int kt) {
        const int p = kt & 3;
        const _Float16* ap = As + p * 8192 + (wm + lr) * 32 + lk * 8;
        const _Float16* bp = Bs + p * 8192 + (wn + lr) * 32 + lk * 8;
        half8 af[8], bf[4];
        #pragma unroll
        for (int mi = 0; mi < 8; mi++)
            af[mi] = *reinterpret_cast<const half8*>(ap + mi * 16 * 32);
        #pragma unroll
        for (int ni = 0; ni < 4; ni++)
            bf[ni] = *reinterpret_cast<const half8*>(bp + ni * 16 * 32);
        __builtin_amdgcn_s_setprio(1);
        #pragma unroll
        for (int mi = 0; mi < 8; mi++)
            #pragma unroll
            for (int ni = 0; ni < 4; ni++)
                acc[mi][ni] = __builtin_amdgcn_mfma_f32_16x16x32_f16(af[mi], bf[ni], acc[mi][ni], 0, 0, 0);
        __builtin_amdgcn_s_setprio(0);
    };

    // prologue: fill buffers 0,1,2
    stage(0); stage(1); stage(2);
    asm volatile("s_waitcnt vmcnt(8)" ::: "memory");   // kt=0 landed (per-wave)
    __builtin_amdgcn_s_barrier();                      // -> landed for all waves

    // main loop: NK = 1024/32 = 32 K-tiles; iterations 0..28 stage kt+3
    for (int kt = 0; kt < 29; ++kt) {
        stage(kt + 3);          // overwrites buf (kt-1)&3, retired at end of kt-1
        compute(kt);
        asm volatile("s_waitcnt vmcnt(8)" ::: "memory");  // kt+1 landed; kt+2,kt+3 in flight
        __builtin_amdgcn_s_barrier();
    }
    // epilogue: drain 8 -> 4 -> 0
    compute(29);
    asm volatile("s_waitcnt vmcnt(4)" ::: "memory");      // kt=30 landed
    __builtin_amdgcn_s_barrier();
    compute(30);
    asm volatile("s_waitcnt vmcnt(0)" ::: "memory");      // kt=31 landed
    __builtin_amdgcn_s_barrier();
    compute(31);

    // epilogue: C/D layout col = lane&15 (n), row = (lane>>4)*4 + reg (m)
    #pragma unroll
    for (int mi = 0; mi < 8; mi++) {
        #pragma unroll
        for (int ni = 0; ni < 4; ni++) {
            #pragma unroll
            for (int reg = 0; reg < 4; reg++) {
                int mm = m0 + wm + mi * 16 + (lane >> 4) * 4 + reg;
                int nn = n0 + wn + ni * 16 + (lane & 15);
                float v = acc[mi][ni][reg];
                if (which == 2) v = 1.0f / (1.0f + __expf(-v));
                out[(size_t)mm * Cdim + nn] = (_Float16)v;
            }
        }
    }
}

// ---------------- Kernel 3: chunk-local WKV totals (zero-start) ----------------
__global__ __launch_bounds__(256) void scan_pass1(const _Float16* __restrict__ kb,
                                                  const _Float16* __restrict__ vb,
                                                  const float* __restrict__ tdecay,
                                                  float* __restrict__ tot_a,
                                                  float* __restrict__ tot_b,
                                                  float* __restrict__ tot_p) {
    int idx = blockIdx.x * 256 + threadIdx.x;   // 0 .. NCHUNK*BC-1
    int j = idx >> 13;
    int bc = idx & (BC - 1);
    int b = bc >> 10;
    int c = bc & (Cdim - 1);
    float w = -__expf(tdecay[c]);
    float aa = 0.0f, bb = 0.0f, pp = -1e30f;
    const _Float16* kp = kb + ((size_t)(b * Tdim + j * CHUNK)) * Cdim + c;
    const _Float16* vp = vb + ((size_t)(b * Tdim + j * CHUNK)) * Cdim + c;
    #pragma unroll 4
    for (int t = 0; t < CHUNK; t++) {
        float kt = (float)kp[(size_t)t * Cdim];
        float vt = (float)vp[(size_t)t * Cdim];
        float ww2 = pp + w;
        float p2 = fmaxf(ww2, kt);
        float e1 = __expf(ww2 - p2);
        float e2 = __expf(kt - p2);
        aa = e1 * aa + e2 * vt;
        bb = e1 * bb + e2;
        pp = p2;
    }
    tot_a[idx] = aa; tot_b[idx] = bb; tot_p[idx] = pp;
}

// ---------------- Kernel 4: sequential combine of chunk totals ----------------
__global__ __launch_bounds__(256) void combine_chunks(const float* __restrict__ tot_a,
                                                      const float* __restrict__ tot_b,
                                                      const float* __restrict__ tot_p,
                                                      const float* __restrict__ aa_init,
                                                      const float* __restrict__ bb_init,
                                                      const float* __restrict__ pp_init,
                                                      const float* __restrict__ tdecay,
                                                      float* __restrict__ inc_a,
                                                      float* __restrict__ inc_b,
                                                      float* __restrict__ inc_p) {
    int idx = blockIdx.x * 256 + threadIdx.x;   // 0 .. BC-1
    int c = idx & (Cdim - 1);
    float w = -__expf(tdecay[c]);
    float wL = w * (float)CHUNK;
    float a = aa_init[idx], b = bb_init[idx], p = pp_init[idx];
    for (int j = 0; j < NCHUNK; j++) {
        inc_a[j * BC + idx] = a;
        inc_b[j * BC + idx] = b;
        inc_p[j * BC + idx] = p;
        float ta = tot_a[j * BC + idx];
        float tb = tot_b[j * BC + idx];
        float tp = tot_p[j * BC + idx];
        float px = p + wL;
        float q = fmaxf(px, tp);
        float e1 = __expf(px - q);
        float e2 = __expf(tp - q);
        a = e1 * a + e2 * ta;
        b = e1 * b + e2 * tb;
        p = q;
    }
}

// ---------------- Kernel 5: replay with incoming state ----------------
__global__ __launch_bounds__(256) void scan_pass2(const _Float16* __restrict__ kb,
                                                  const _Float16* __restrict__ vb,
                                                  const _Float16* __restrict__ rb,
                                                  const float* __restrict__ tdecay,
                                                  const float* __restrict__ tfirst,
                                                  const float* __restrict__ inc_a,
                                                  const float* __restrict__ inc_b,
                                                  const float* __restrict__ inc_p,
                                                  float* __restrict__ partial,
                                                  float* __restrict__ ylast) {
    int idx = blockIdx.x * 256 + threadIdx.x;
    int j = idx >> 13;
    int bc = idx & (BC - 1);
    int b = bc >> 10;
    int c = bc & (Cdim - 1);
    float w = -__expf(tdecay[c]);
    float u = tfirst[c];
    float aa = inc_a[idx], bb = inc_b[idx], pp = inc_p[idx];
    const size_t base = ((size_t)(b * Tdim + j * CHUNK)) * Cdim + c;
    const _Float16* kp = kb + base;
    const _Float16* vp = vb + base;
    const _Float16* rp = rb + base;
    float sum = 0.0f, ylv = 0.0f;
    #pragma unroll 4
    for (int t = 0; t < CHUNK; t++) {
        float kt = (float)kp[(size_t)t * Cdim];
        float vt = (float)vp[(size_t)t * Cdim];
        float rt = (float)rp[(size_t)t * Cdim];
        float ww = u + kt;
        float p = fmaxf(pp, ww);
        float e1 = __expf(pp - p);
        float e2 = __expf(ww - p);
        float wkv = (e1 * aa + e2 * vt) / (e1 * bb + e2);
        float y = rt * wkv;
        sum += y;
        ylv = y;
        float ww2 = pp + w;
        float p2 = fmaxf(ww2, kt);
        float e1b = __expf(ww2 - p2);
        float e2b = __expf(kt - p2);
        aa = e1b * aa + e2b * vt;
        bb = e1b * bb + e2b;
        pp = p2;
    }
    partial[idx] = sum;
    if (j == NCHUNK - 1) ylast[bc] = ylv;
}

// ---------------- Kernel 6: z[b,c] = 0.5*(y_last + mean_t y) ----------------
__global__ __launch_bounds__(256) void reduce_z(const float* __restrict__ partial,
                                                const float* __restrict__ ylast,
                                                float* __restrict__ z) {
    int idx = blockIdx.x * 256 + threadIdx.x;   // 0..BC-1
    float s = 0.0f;
    for (int j = 0; j < NCHUNK; j++) s += partial[j * BC + idx];
    z[idx] = 0.5f * (ylast[idx] + s * (1.0f / (float)Tdim));
}

// ---------------- Kernel 7: hx[b,d] = sum_c z[b,c]*Wo[d,c]; write twice ----------------
__global__ __launch_bounds__(256) void final_out(const float* __restrict__ z,
                                                 const float* __restrict__ Wo,
                                                 float* __restrict__ out) {
    int gw = (blockIdx.x * 256 + threadIdx.x) >> 6;   // global wave id, 0..BC-1
    int lane = threadIdx.x & 63;
    int b = gw >> 10;
    int d = gw & (Cdim - 1);
    const float* zr = z + (size_t)b * Cdim;
    const float* wr = Wo + (size_t)d * Cdim;
    float acc = 0.0f;
    #pragma unroll
    for (int i = lane; i < Cdim; i += 64) acc += zr[i] * wr[i];
    #pragma unroll
    for (int off = 32; off > 0; off >>= 1) acc += __shfl_down(acc, off);
    if (lane == 0) {
        out[(size_t)b * Cdim + d] = acc;
        out[(size_t)BC + (size_t)b * Cdim + d] = acc;
    }
}

extern "C" void kernel_launch(void* const* d_in, const int* in_sizes, int n_in,
                              void* d_out, int out_size, void* d_ws, size_t ws_size,
                              hipStream_t stream) {
    const int*   tokens  = (const int*)d_in[0];
    const float* xx_init = (const float*)d_in[1];
    const float* aa_init = (const float*)d_in[2];
    const float* bb_init = (const float*)d_in[3];
    const float* pp_init = (const float*)d_in[4];
    const float* emb     = (const float*)d_in[5];
    const float* tmk     = (const float*)d_in[6];
    const float* tmv     = (const float*)d_in[7];
    const float* tmr     = (const float*)d_in[8];
    const float* tdecay  = (const float*)d_in[9];
    const float* tfirst  = (const float*)d_in[10];
    const float* Wk      = (const float*)d_in[11];
    const float* Wv      = (const float*)d_in[12];
    const float* Wr      = (const float*)d_in[13];
    const float* Wo      = (const float*)d_in[14];
    float* out = (float*)d_out;

    char* ws = (char*)d_ws;
    size_t off = 0;
    auto alloc = [&](size_t bytes) -> void* {
        void* p = ws + off;
        off += (bytes + 255) & ~(size_t)255;
        return p;
    };
    _Float16* xe = (_Float16*)alloc((size_t)Bdim * (Tdim + 1) * Cdim * 2);
    _Float16* xkb = (_Float16*)alloc((size_t)Bdim * Tdim * Cdim * 2);
    _Float16* xvb = (_Float16*)alloc((size_t)Bdim * Tdim * Cdim * 2);
    _Float16* xrb = (_Float16*)alloc((size_t)Bdim * Tdim * Cdim * 2);
    _Float16* kb = xe;   // alias: xe dead after mix3
    _Float16* vb = (_Float16*)alloc((size_t)Bdim * Tdim * Cdim * 2);
    _Float16* rb = (_Float16*)alloc((size_t)Bdim * Tdim * Cdim * 2);
    _Float16* Wh = (_Float16*)alloc((size_t)3 * Cdim * Cdim * 2);
    float* tot_a = (float*)alloc((size_t)NCHUNK * BC * 4);
    float* tot_b = (float*)alloc((size_t)NCHUNK * BC * 4);
    float* tot_p = (float*)alloc((size_t)NCHUNK * BC * 4);
    float* inc_a = (float*)alloc((size_t)NCHUNK * BC * 4);
    float* inc_b = (float*)alloc((size_t)NCHUNK * BC * 4);
    float* inc_p = (float*)alloc((size_t)NCHUNK * BC * 4);
    float* partial = (float*)alloc((size_t)NCHUNK * BC * 4);
    float* ylast   = (float*)alloc((size_t)BC * 4);
    float* zbuf    = (float*)alloc((size_t)BC * 4);

    embed_mix<<<Bdim * (Tdim + 1), 256, 0, stream>>>(tokens, xx_init, emb, xe);
    mix3<<<Bdim * Tdim, 256, 0, stream>>>(xe, tmk, tmv, tmr, xkb, xvb, xrb);
    wconv<<<dim3(1024, 3), 256, 0, stream>>>(Wk, Wv, Wr, Wh);
    gemm_kvr<<<dim3(256, 3), 512, 0, stream>>>(xkb, xvb, xrb, Wh, kb, vb, rb);
    scan_pass1<<<(NCHUNK * BC) / 256, 256, 0, stream>>>(kb, vb, tdecay, tot_a, tot_b, tot_p);
    combine_chunks<<<BC / 256, 256, 0, stream>>>(tot_a, tot_b, tot_p, aa_init, bb_init, pp_init,
                                                 tdecay, inc_a, inc_b, inc_p);
    scan_pass2<<<(NCHUNK * BC) / 256, 256, 0, stream>>>(kb, vb, rb, tdecay, tfirst,
                                                        inc_a, inc_b, inc_p, partial, ylast);
    reduce_z<<<BC / 256, 256, 0, stream>>>(partial, ylast, zbuf);
    final_out<<<(BC / 4), 256, 0, stream>>>(zbuf, Wo, out);
}

// Round 3
// 410.583 us; speedup vs baseline: 1.0205x; 1.0142x over previous
//
#include <hip/hip_runtime.h>

#define Bdim 8
#define Tdim 2048
#define Cdim 1024
#define CHUNK 128
#define NCHUNK 16
#define BC (Bdim*Cdim)

typedef float floatx4 __attribute__((ext_vector_type(4)));
typedef _Float16 half8 __attribute__((ext_vector_type(8)));
typedef _Float16 half4v __attribute__((ext_vector_type(4)));

__device__ __forceinline__ void load16(const void* g, void* l) {
    __builtin_amdgcn_global_load_lds(
        (const __attribute__((address_space(1))) void*)g,
        (__attribute__((address_space(3))) void*)l, 16, 0, 0);
}

// ---------------- Kernel 1: embedding gather + shift row, fp32 -> f16 ----------------
__global__ __launch_bounds__(256) void embed_mix(const int* __restrict__ tokens,
                                                 const float* __restrict__ xx_init,
                                                 const float* __restrict__ emb,
                                                 _Float16* __restrict__ xe) {
    int row = blockIdx.x;              // 0 .. B*(T+1)-1
    int b = row / (Tdim + 1);
    int tt = row % (Tdim + 1);
    const float* src;
    if (tt == 0) src = xx_init + (size_t)b * Cdim;
    else         src = emb + (size_t)tokens[b * Tdim + tt - 1] * Cdim;
    int c0 = threadIdx.x * 4;
    float4 f = *reinterpret_cast<const float4*>(src + c0);
    half4v h;
    h[0] = (_Float16)f.x; h[1] = (_Float16)f.y; h[2] = (_Float16)f.z; h[3] = (_Float16)f.w;
    *reinterpret_cast<half4v*>(xe + (size_t)row * Cdim + c0) = h;
}

// ---------------- Kernel 1b: time-mix precompute, f16 in -> f16 out (x3) ----------------
__global__ __launch_bounds__(256) void mix3(const _Float16* __restrict__ xe,
                                            const float* __restrict__ tmk,
                                            const float* __restrict__ tmv,
                                            const float* __restrict__ tmr,
                                            _Float16* __restrict__ xk,
                                            _Float16* __restrict__ xv,
                                            _Float16* __restrict__ xr) {
    int row = blockIdx.x;              // b*T + t
    int b = row >> 11;
    int t = row & (Tdim - 1);
    const _Float16* cur = xe + ((size_t)(b * (Tdim + 1) + t + 1)) * Cdim;
    const _Float16* prv = cur - Cdim;
    int c = threadIdx.x * 4;
    half4v cu = *reinterpret_cast<const half4v*>(cur + c);
    half4v pv = *reinterpret_cast<const half4v*>(prv + c);
    float4 mk = *reinterpret_cast<const float4*>(tmk + c);
    float4 mv = *reinterpret_cast<const float4*>(tmv + c);
    float4 mr = *reinterpret_cast<const float4*>(tmr + c);
    half4v hk, hv, hr;
    float cf[4] = {(float)cu[0], (float)cu[1], (float)cu[2], (float)cu[3]};
    float pf[4] = {(float)pv[0], (float)pv[1], (float)pv[2], (float)pv[3]};
    float mkf[4] = {mk.x, mk.y, mk.z, mk.w};
    float mvf[4] = {mv.x, mv.y, mv.z, mv.w};
    float mrf[4] = {mr.x, mr.y, mr.z, mr.w};
    #pragma unroll
    for (int j = 0; j < 4; j++) {
        hk[j] = (_Float16)(mkf[j] * cf[j] + (1.0f - mkf[j]) * pf[j]);
        hv[j] = (_Float16)(mvf[j] * cf[j] + (1.0f - mvf[j]) * pf[j]);
        hr[j] = (_Float16)(mrf[j] * cf[j] + (1.0f - mrf[j]) * pf[j]);
    }
    size_t o = (size_t)row * Cdim + c;
    *reinterpret_cast<half4v*>(xk + o) = hk;
    *reinterpret_cast<half4v*>(xv + o) = hv;
    *reinterpret_cast<half4v*>(xr + o) = hr;
}

// ---------------- Kernel 1c: W fp32 -> f16 ----------------
__global__ __launch_bounds__(256) void wconv(const float* __restrict__ Wk,
                                             const float* __restrict__ Wv,
                                             const float* __restrict__ Wr,
                                             _Float16* __restrict__ Wh) {
    const float* W = blockIdx.y == 0 ? Wk : (blockIdx.y == 1 ? Wv : Wr);
    _Float16* dst = Wh + (size_t)blockIdx.y * Cdim * Cdim;
    int i = (blockIdx.x * 256 + threadIdx.x) * 4;
    float4 f = *reinterpret_cast<const float4*>(W + i);
    half4v h;
    h[0] = (_Float16)f.x; h[1] = (_Float16)f.y; h[2] = (_Float16)f.z; h[3] = (_Float16)f.w;
    *reinterpret_cast<half4v*>(dst + i) = h;
}

// ---------------- Kernel 2: deep-pipelined f16 GEMM (NT), 256x256 tile, BK=32 ----------------
// out[m,n] = sum_c X[m,c] * W[n,c];  which=2 gets sigmoid.
// 4 LDS buffers, stage 3 K-tiles ahead, counted s_waitcnt vmcnt(8), 1 barrier/K-tile.
// XOR swizzle swz(r)=(r>>1)&3 (rule #21: linear LDS dest for global_load_lds,
// inverse-swizzled GLOBAL source, same swizzle on ds_read).  Within each 16-lane
// read phase every 4-bank group is hit by exactly 2 lanes = b128 minimum.
__global__ __launch_bounds__(512, 2) void gemm_kvr(const _Float16* __restrict__ xk,
                                                   const _Float16* __restrict__ xv,
                                                   const _Float16* __restrict__ xr,
                                                   const _Float16* __restrict__ Wh,
                                                   _Float16* __restrict__ ko,
                                                   _Float16* __restrict__ vo,
                                                   _Float16* __restrict__ ro) {
    const int which = blockIdx.y;
    const _Float16* X = which == 0 ? xk : (which == 1 ? xv : xr);
    const _Float16* W = Wh + (size_t)which * Cdim * Cdim;
    _Float16* out     = which == 0 ? ko : (which == 1 ? vo : ro);

    // XCD-aware swizzle: all 4 n-tiles of one m-tile group on the same XCD
    const int lin = blockIdx.x;        // 0..255
    const int xcd = lin & 7;
    const int loc = lin >> 3;          // 0..31
    const int mt = xcd * 8 + (loc >> 2);   // 0..63
    const int nt = loc & 3;                // 0..3
    const int m0 = mt * 256;
    const int n0 = nt * 256;

    // 4 K-tile buffers: 4 * (16KB A + 16KB B) = 128 KB
    __shared__ _Float16 As[4 * 8192];
    __shared__ _Float16 Bs[4 * 8192];

    const int tid = threadIdx.x;
    const int lane = tid & 63;
    const int wave = tid >> 6;         // 0..7
    const int wm = (wave >> 2) * 128;  // 2 M-groups
    const int wn = (wave & 3) * 64;    // 4 N-groups
    const int lr = lane & 15;          // fragment row within 16
    const int lk = lane >> 4;          // fragment k-block 0..3
    const int sw = (lr >> 1) & 3;      // row-swizzle, invariant across mi/ni (16>>1 & 3 == 0)

    const _Float16* Asrc = X + (size_t)m0 * Cdim;
    const _Float16* Bsrc = W + (size_t)n0 * Cdim;

    floatx4 acc[8][4] = {};

    // stage K-tile kt into buffer kt&3 (4 global_load_lds per thread).
    // LDS dest linear (slot e); global source colblock pre-swizzled: cl = cp ^ swz(r).
    auto stage = [&](int kt) {
        const int p = kt & 3;
        const int k0 = kt * 32;
        #pragma unroll
        for (int i = 0; i < 2; i++) {
            int e = i * 512 + tid;         // 16B slot index, 0..1023
            int r = e >> 2;                // tile row 0..255
            int cp = e & 3;                // physical colblock
            int cl = cp ^ ((r >> 1) & 3);  // logical (global) colblock
            load16(Asrc + (size_t)r * Cdim + k0 + cl * 8, (char*)(As + p * 8192) + e * 16);
        }
        #pragma unroll
        for (int i = 0; i < 2; i++) {
            int e = i * 512 + tid;
            int r = e >> 2;
            int cp = e & 3;
            int cl = cp ^ ((r >> 1) & 3);
            load16(Bsrc + (size_t)r * Cdim + k0 + cl * 8, (char*)(Bs + p * 8192) + e * 16);
        }
    };

    // ds_read fragments from buffer kt&3 (swizzled slots) and run 32 MFMAs
    auto compute = [&](int kt) {
        const int p = kt & 3;
        const _Float16* ap = As + p * 8192 + (wm + lr) * 32 + (lk ^ sw) * 8;
        const _Float16* bp = Bs + p * 8192 + (wn + lr) * 32 + (lk ^ sw) * 8;
        half8 af[8], bf[4];
        #pragma unroll
        for (int mi = 0; mi < 8; mi++)
            af[mi] = *reinterpret_cast<const half8*>(ap + mi * 16 * 32);
        #pragma unroll
        for (int ni = 0; ni < 4; ni++)
            bf[ni] = *reinterpret_cast<const half8*>(bp + ni * 16 * 32);
        __builtin_amdgcn_s_setprio(1);
        #pragma unroll
        for (int mi = 0; mi < 8; mi++)
            #pragma unroll
            for (int ni = 0; ni < 4; ni++)
                acc[mi][ni] = __builtin_amdgcn_mfma_f32_16x16x32_f16(af[mi], bf[ni], acc[mi][ni], 0, 0, 0);
        __builtin_amdgcn_s_setprio(0);
    };

    // prologue: fill buffers 0,1,2
    stage(0); stage(1); stage(2);
    asm volatile("s_waitcnt vmcnt(8)" ::: "memory");   // kt=0 landed (per-wave)
    __builtin_amdgcn_s_barrier();                      // -> landed for all waves

    // main loop: NK = 1024/32 = 32 K-tiles; iterations 0..28 stage kt+3
    for (int kt = 0; kt < 29; ++kt) {
        stage(kt + 3);          // overwrites buf (kt-1)&3, retired at end of kt-1
        compute(kt);
        asm volatile("s_waitcnt vmcnt(8)" ::: "memory");  // kt+1 landed; kt+2,kt+3 in flight
        __builtin_amdgcn_s_barrier();
    }
    // epilogue: drain 8 -> 4 -> 0
    compute(29);
    asm volatile("s_waitcnt vmcnt(4)" ::: "memory");      // kt=30 landed
    __builtin_amdgcn_s_barrier();
    compute(30);
    asm volatile("s_waitcnt vmcnt(0)" ::: "memory");      // kt=31 landed
    __builtin_amdgcn_s_barrier();
    compute(31);

    // epilogue: C/D layout col = lane&15 (n), row = (lane>>4)*4 + reg (m)
    #pragma unroll
    for (int mi = 0; mi < 8; mi++) {
        #pragma unroll
        for (int ni = 0; ni < 4; ni++) {
            #pragma unroll
            for (int reg = 0; reg < 4; reg++) {
                int mm = m0 + wm + mi * 16 + (lane >> 4) * 4 + reg;
                int nn = n0 + wn + ni * 16 + (lane & 15);
                float v = acc[mi][ni][reg];
                if (which == 2) v = 1.0f / (1.0f + __expf(-v));
                out[(size_t)mm * Cdim + nn] = (_Float16)v;
            }
        }
    }
}

// ---------------- Kernel 3: chunk-local WKV totals (zero-start) ----------------
__global__ __launch_bounds__(256) void scan_pass1(const _Float16* __restrict__ kb,
                                                  const _Float16* __restrict__ vb,
                                                  const float* __restrict__ tdecay,
                                                  float* __restrict__ tot_a,
                                                  float* __restrict__ tot_b,
                                                  float* __restrict__ tot_p) {
    int idx = blockIdx.x * 256 + threadIdx.x;   // 0 .. NCHUNK*BC-1
    int j = idx >> 13;
    int bc = idx & (BC - 1);
    int b = bc >> 10;
    int c = bc & (Cdim - 1);
    float w = -__expf(tdecay[c]);
    float aa = 0.0f, bb = 0.0f, pp = -1e30f;
    const _Float16* kp = kb + ((size_t)(b * Tdim + j * CHUNK)) * Cdim + c;
    const _Float16* vp = vb + ((size_t)(b * Tdim + j * CHUNK)) * Cdim + c;
    #pragma unroll 4
    for (int t = 0; t < CHUNK; t++) {
        float kt = (float)kp[(size_t)t * Cdim];
        float vt = (float)vp[(size_t)t * Cdim];
        float ww2 = pp + w;
        float p2 = fmaxf(ww2, kt);
        float e1 = __expf(ww2 - p2);
        float e2 = __expf(kt - p2);
        aa = e1 * aa + e2 * vt;
        bb = e1 * bb + e2;
        pp = p2;
    }
    tot_a[idx] = aa; tot_b[idx] = bb; tot_p[idx] = pp;
}

// ---------------- Kernel 4: sequential combine of chunk totals ----------------
__global__ __launch_bounds__(256) void combine_chunks(const float* __restrict__ tot_a,
                                                      const float* __restrict__ tot_b,
                                                      const float* __restrict__ tot_p,
                                                      const float* __restrict__ aa_init,
                                                      const float* __restrict__ bb_init,
                                                      const float* __restrict__ pp_init,
                                                      const float* __restrict__ tdecay,
                                                      float* __restrict__ inc_a,
                                                      float* __restrict__ inc_b,
                                                      float* __restrict__ inc_p) {
    int idx = blockIdx.x * 256 + threadIdx.x;   // 0 .. BC-1
    int c = idx & (Cdim - 1);
    float w = -__expf(tdecay[c]);
    float wL = w * (float)CHUNK;
    float a = aa_init[idx], b = bb_init[idx], p = pp_init[idx];
    for (int j = 0; j < NCHUNK; j++) {
        inc_a[j * BC + idx] = a;
        inc_b[j * BC + idx] = b;
        inc_p[j * BC + idx] = p;
        float ta = tot_a[j * BC + idx];
        float tb = tot_b[j * BC + idx];
        float tp = tot_p[j * BC + idx];
        float px = p + wL;
        float q = fmaxf(px, tp);
        float e1 = __expf(px - q);
        float e2 = __expf(tp - q);
        a = e1 * a + e2 * ta;
        b = e1 * b + e2 * tb;
        p = q;
    }
}

// ---------------- Kernel 5: replay with incoming state ----------------
__global__ __launch_bounds__(256) void scan_pass2(const _Float16* __restrict__ kb,
                                                  const _Float16* __restrict__ vb,
                                                  const _Float16* __restrict__ rb,
                                                  const float* __restrict__ tdecay,
                                                  const float* __restrict__ tfirst,
                                                  const float* __restrict__ inc_a,
                                                  const float* __restrict__ inc_b,
                                                  const float* __restrict__ inc_p,
                                                  float* __restrict__ partial,
                                                  float* __restrict__ ylast) {
    int idx = blockIdx.x * 256 + threadIdx.x;
    int j = idx >> 13;
    int bc = idx & (BC - 1);
    int b = bc >> 10;
    int c = bc & (Cdim - 1);
    float w = -__expf(tdecay[c]);
    float u = tfirst[c];
    float aa = inc_a[idx], bb = inc_b[idx], pp = inc_p[idx];
    const size_t base = ((size_t)(b * Tdim + j * CHUNK)) * Cdim + c;
    const _Float16* kp = kb + base;
    const _Float16* vp = vb + base;
    const _Float16* rp = rb + base;
    float sum = 0.0f, ylv = 0.0f;
    #pragma unroll 4
    for (int t = 0; t < CHUNK; t++) {
        float kt = (float)kp[(size_t)t * Cdim];
        float vt = (float)vp[(size_t)t * Cdim];
        float rt = (float)rp[(size_t)t * Cdim];
        float ww = u + kt;
        float p = fmaxf(pp, ww);
        float e1 = __expf(pp - p);
        float e2 = __expf(ww - p);
        float wkv = (e1 * aa + e2 * vt) / (e1 * bb + e2);
        float y = rt * wkv;
        sum += y;
        ylv = y;
        float ww2 = pp + w;
        float p2 = fmaxf(ww2, kt);
        float e1b = __expf(ww2 - p2);
        float e2b = __expf(kt - p2);
        aa = e1b * aa + e2b * vt;
        bb = e1b * bb + e2b;
        pp = p2;
    }
    partial[idx] = sum;
    if (j == NCHUNK - 1) ylast[bc] = ylv;
}

// ---------------- Kernel 6: z[b,c] = 0.5*(y_last + mean_t y) ----------------
__global__ __launch_bounds__(256) void reduce_z(const float* __restrict__ partial,
                                                const float* __restrict__ ylast,
                                                float* __restrict__ z) {
    int idx = blockIdx.x * 256 + threadIdx.x;   // 0..BC-1
    float s = 0.0f;
    for (int j = 0; j < NCHUNK; j++) s += partial[j * BC + idx];
    z[idx] = 0.5f * (ylast[idx] + s * (1.0f / (float)Tdim));
}

// ---------------- Kernel 7: hx[b,d] = sum_c z[b,c]*Wo[d,c]; write twice ----------------
__global__ __launch_bounds__(256) void final_out(const float* __restrict__ z,
                                                 const float* __restrict__ Wo,
                                                 float* __restrict__ out) {
    int gw = (blockIdx.x * 256 + threadIdx.x) >> 6;   // global wave id, 0..BC-1
    int lane = threadIdx.x & 63;
    int b = gw >> 10;
    int d = gw & (Cdim - 1);
    const float* zr = z + (size_t)b * Cdim;
    const float* wr = Wo + (size_t)d * Cdim;
    float acc = 0.0f;
    #pragma unroll
    for (int i = lane; i < Cdim; i += 64) acc += zr[i] * wr[i];
    #pragma unroll
    for (int off = 32; off > 0; off >>= 1) acc += __shfl_down(acc, off);
    if (lane == 0) {
        out[(size_t)b * Cdim + d] = acc;
        out[(size_t)BC + (size_t)b * Cdim + d] = acc;
    }
}

extern "C" void kernel_launch(void* const* d_in, const int* in_sizes, int n_in,
                              void* d_out, int out_size, void* d_ws, size_t ws_size,
                              hipStream_t stream) {
    const int*   tokens  = (const int*)d_in[0];
    const float* xx_init = (const float*)d_in[1];
    const float* aa_init = (const float*)d_in[2];
    const float* bb_init = (const float*)d_in[3];
    const float* pp_init = (const float*)d_in[4];
    const float* emb     = (const float*)d_in[5];
    const float* tmk     = (const float*)d_in[6];
    const float* tmv     = (const float*)d_in[7];
    const float* tmr     = (const float*)d_in[8];
    const float* tdecay  = (const float*)d_in[9];
    const float* tfirst  = (const float*)d_in[10];
    const float* Wk      = (const float*)d_in[11];
    const float* Wv      = (const float*)d_in[12];
    const float* Wr      = (const float*)d_in[13];
    const float* Wo      = (const float*)d_in[14];
    float* out = (float*)d_out;

    char* ws = (char*)d_ws;
    size_t off = 0;
    auto alloc = [&](size_t bytes) -> void* {
        void* p = ws + off;
        off += (bytes + 255) & ~(size_t)255;
        return p;
    };
    _Float16* xe = (_Float16*)alloc((size_t)Bdim * (Tdim + 1) * Cdim * 2);
    _Float16* xkb = (_Float16*)alloc((size_t)Bdim * Tdim * Cdim * 2);
    _Float16* xvb = (_Float16*)alloc((size_t)Bdim * Tdim * Cdim * 2);
    _Float16* xrb = (_Float16*)alloc((size_t)Bdim * Tdim * Cdim * 2);
    _Float16* kb = xe;   // alias: xe dead after mix3
    _Float16* vb = (_Float16*)alloc((size_t)Bdim * Tdim * Cdim * 2);
    _Float16* rb = (_Float16*)alloc((size_t)Bdim * Tdim * Cdim * 2);
    _Float16* Wh = (_Float16*)alloc((size_t)3 * Cdim * Cdim * 2);
    float* tot_a = (float*)alloc((size_t)NCHUNK * BC * 4);
    float* tot_b = (float*)alloc((size_t)NCHUNK * BC * 4);
    float* tot_p = (float*)alloc((size_t)NCHUNK * BC * 4);
    float* inc_a = (float*)alloc((size_t)NCHUNK * BC * 4);
    float* inc_b = (float*)alloc((size_t)NCHUNK * BC * 4);
    float* inc_p = (float*)alloc((size_t)NCHUNK * BC * 4);
    float* partial = (float*)alloc((size_t)NCHUNK * BC * 4);
    float* ylast   = (float*)alloc((size_t)BC * 4);
    float* zbuf    = (float*)alloc((size_t)BC * 4);

    embed_mix<<<Bdim * (Tdim + 1), 256, 0, stream>>>(tokens, xx_init, emb, xe);
    mix3<<<Bdim * Tdim, 256, 0, stream>>>(xe, tmk, tmv, tmr, xkb, xvb, xrb);
    wconv<<<dim3(1024, 3), 256, 0, stream>>>(Wk, Wv, Wr, Wh);
    gemm_kvr<<<dim3(256, 3), 512, 0, stream>>>(xkb, xvb, xrb, Wh, kb, vb, rb);
    scan_pass1<<<(NCHUNK * BC) / 256, 256, 0, stream>>>(kb, vb, tdecay, tot_a, tot_b, tot_p);
    combine_chunks<<<BC / 256, 256, 0, stream>>>(tot_a, tot_b, tot_p, aa_init, bb_init, pp_init,
                                                 tdecay, inc_a, inc_b, inc_p);
    scan_pass2<<<(NCHUNK * BC) / 256, 256, 0, stream>>>(kb, vb, rb, tdecay, tfirst,
                                                        inc_a, inc_b, inc_p, partial, ylast);
    reduce_z<<<BC / 256, 256, 0, stream>>>(partial, ylast, zbuf);
    final_out<<<(BC / 4), 256, 0, stream>>>(zbuf, Wo, out);
}

// Round 4
// 410.260 us; speedup vs baseline: 1.0213x; 1.0008x over previous
//
#include <hip/hip_runtime.h>

#define Bdim 8
#define Tdim 2048
#define Cdim 1024
#define CHUNK 128
#define NCHUNK 16
#define BC (Bdim*Cdim)

typedef float floatx4 __attribute__((ext_vector_type(4)));
typedef _Float16 half8 __attribute__((ext_vector_type(8)));
typedef _Float16 half4v __attribute__((ext_vector_type(4)));

__device__ __forceinline__ void load16(const void* g, void* l) {
    __builtin_amdgcn_global_load_lds(
        (const __attribute__((address_space(1))) void*)g,
        (__attribute__((address_space(3))) void*)l, 16, 0, 0);
}

// ---------------- Kernel 1: embedding gather + shift row, fp32 -> f16 ----------------
__global__ __launch_bounds__(256) void embed_mix(const int* __restrict__ tokens,
                                                 const float* __restrict__ xx_init,
                                                 const float* __restrict__ emb,
                                                 _Float16* __restrict__ xe) {
    int row = blockIdx.x;              // 0 .. B*(T+1)-1
    int b = row / (Tdim + 1);
    int tt = row % (Tdim + 1);
    const float* src;
    if (tt == 0) src = xx_init + (size_t)b * Cdim;
    else         src = emb + (size_t)tokens[b * Tdim + tt - 1] * Cdim;
    int c0 = threadIdx.x * 4;
    float4 f = *reinterpret_cast<const float4*>(src + c0);
    half4v h;
    h[0] = (_Float16)f.x; h[1] = (_Float16)f.y; h[2] = (_Float16)f.z; h[3] = (_Float16)f.w;
    *reinterpret_cast<half4v*>(xe + (size_t)row * Cdim + c0) = h;
}

// ---------------- Kernel 1b: time-mix precompute, f16 in -> f16 out (x3) ----------------
__global__ __launch_bounds__(256) void mix3(const _Float16* __restrict__ xe,
                                            const float* __restrict__ tmk,
                                            const float* __restrict__ tmv,
                                            const float* __restrict__ tmr,
                                            _Float16* __restrict__ xk,
                                            _Float16* __restrict__ xv,
                                            _Float16* __restrict__ xr) {
    int row = blockIdx.x;              // b*T + t
    int b = row >> 11;
    int t = row & (Tdim - 1);
    const _Float16* cur = xe + ((size_t)(b * (Tdim + 1) + t + 1)) * Cdim;
    const _Float16* prv = cur - Cdim;
    int c = threadIdx.x * 4;
    half4v cu = *reinterpret_cast<const half4v*>(cur + c);
    half4v pv = *reinterpret_cast<const half4v*>(prv + c);
    float4 mk = *reinterpret_cast<const float4*>(tmk + c);
    float4 mv = *reinterpret_cast<const float4*>(tmv + c);
    float4 mr = *reinterpret_cast<const float4*>(tmr + c);
    half4v hk, hv, hr;
    float cf[4] = {(float)cu[0], (float)cu[1], (float)cu[2], (float)cu[3]};
    float pf[4] = {(float)pv[0], (float)pv[1], (float)pv[2], (float)pv[3]};
    float mkf[4] = {mk.x, mk.y, mk.z, mk.w};
    float mvf[4] = {mv.x, mv.y, mv.z, mv.w};
    float mrf[4] = {mr.x, mr.y, mr.z, mr.w};
    #pragma unroll
    for (int j = 0; j < 4; j++) {
        hk[j] = (_Float16)(mkf[j] * cf[j] + (1.0f - mkf[j]) * pf[j]);
        hv[j] = (_Float16)(mvf[j] * cf[j] + (1.0f - mvf[j]) * pf[j]);
        hr[j] = (_Float16)(mrf[j] * cf[j] + (1.0f - mrf[j]) * pf[j]);
    }
    size_t o = (size_t)row * Cdim + c;
    *reinterpret_cast<half4v*>(xk + o) = hk;
    *reinterpret_cast<half4v*>(xv + o) = hv;
    *reinterpret_cast<half4v*>(xr + o) = hr;
}

// ---------------- Kernel 1c: W fp32 -> f16 ----------------
__global__ __launch_bounds__(256) void wconv(const float* __restrict__ Wk,
                                             const float* __restrict__ Wv,
                                             const float* __restrict__ Wr,
                                             _Float16* __restrict__ Wh) {
    const float* W = blockIdx.y == 0 ? Wk : (blockIdx.y == 1 ? Wv : Wr);
    _Float16* dst = Wh + (size_t)blockIdx.y * Cdim * Cdim;
    int i = (blockIdx.x * 256 + threadIdx.x) * 4;
    float4 f = *reinterpret_cast<const float4*>(W + i);
    half4v h;
    h[0] = (_Float16)f.x; h[1] = (_Float16)f.y; h[2] = (_Float16)f.z; h[3] = (_Float16)f.w;
    *reinterpret_cast<half4v*>(dst + i) = h;
}

// ---------------- Kernel 2: deep-pipelined f16 GEMM (NT), 256x256 tile, BK=32 ----------------
// out[m,n] = sum_c X[m,c] * W[n,c];  which=2 gets sigmoid.
// 4 LDS buffers, stage 3 K-tiles ahead, counted s_waitcnt vmcnt(8).
// Each K-tile split into 2 phases (T3 rhythm): {ds_read subtile ∥ stage half ->
// barrier -> lgkmcnt(0)+sched_barrier -> setprio(1) MFMA x16 setprio(0) -> barrier}.
// XOR swizzle swz(r)=(r>>1)&3 keeps ds_read_b128 conflict-free (rule #21:
// linear LDS dest, inverse-swizzled global source, same swizzle on read).
__global__ __launch_bounds__(512, 2) void gemm_kvr(const _Float16* __restrict__ xk,
                                                   const _Float16* __restrict__ xv,
                                                   const _Float16* __restrict__ xr,
                                                   const _Float16* __restrict__ Wh,
                                                   _Float16* __restrict__ ko,
                                                   _Float16* __restrict__ vo,
                                                   _Float16* __restrict__ ro) {
    const int which = blockIdx.y;
    const _Float16* X = which == 0 ? xk : (which == 1 ? xv : xr);
    const _Float16* W = Wh + (size_t)which * Cdim * Cdim;
    _Float16* out     = which == 0 ? ko : (which == 1 ? vo : ro);

    // XCD-aware swizzle: all 4 n-tiles of one m-tile group on the same XCD
    const int lin = blockIdx.x;        // 0..255
    const int xcd = lin & 7;
    const int loc = lin >> 3;          // 0..31
    const int mt = xcd * 8 + (loc >> 2);   // 0..63
    const int nt = loc & 3;                // 0..3
    const int m0 = mt * 256;
    const int n0 = nt * 256;

    // 4 K-tile buffers: 4 * (16KB A + 16KB B) = 128 KB
    __shared__ _Float16 As[4 * 8192];
    __shared__ _Float16 Bs[4 * 8192];

    const int tid = threadIdx.x;
    const int lane = tid & 63;
    const int wave = tid >> 6;         // 0..7
    const int wm = (wave >> 2) * 128;  // 2 M-groups
    const int wn = (wave & 3) * 64;    // 4 N-groups
    const int lr = lane & 15;          // fragment row within 16
    const int lk = lane >> 4;          // fragment k-block 0..3
    const int sw = (lr >> 1) & 3;      // row-swizzle, invariant across mi/ni

    const _Float16* Asrc = X + (size_t)m0 * Cdim;
    const _Float16* Bsrc = W + (size_t)n0 * Cdim;

    floatx4 acc[8][4] = {};

    // stage half-tiles of K-tile kt into buffer kt&3 (2 loads each).
    // LDS dest linear (slot e); global source colblock pre-swizzled.
    auto stageA = [&](int kt) {
        const int p = kt & 3;
        const int k0 = kt * 32;
        #pragma unroll
        for (int i = 0; i < 2; i++) {
            int e = i * 512 + tid;         // 16B slot index, 0..1023
            int r = e >> 2;                // tile row 0..255
            int cp = e & 3;                // physical colblock
            int cl = cp ^ ((r >> 1) & 3);  // logical (global) colblock
            load16(Asrc + (size_t)r * Cdim + k0 + cl * 8, (char*)(As + p * 8192) + e * 16);
        }
    };
    auto stageB = [&](int kt) {
        const int p = kt & 3;
        const int k0 = kt * 32;
        #pragma unroll
        for (int i = 0; i < 2; i++) {
            int e = i * 512 + tid;
            int r = e >> 2;
            int cp = e & 3;
            int cl = cp ^ ((r >> 1) & 3);
            load16(Bsrc + (size_t)r * Cdim + k0 + cl * 8, (char*)(Bs + p * 8192) + e * 16);
        }
    };

    // two-phase K-tile: reads/MFMAs interleaved with stage issues (T3 rhythm)
    auto ktile = [&](int kt, bool st) {
        const int p = kt & 3;
        const _Float16* ap = As + p * 8192 + (wm + lr) * 32 + (lk ^ sw) * 8;
        const _Float16* bp = Bs + p * 8192 + (wn + lr) * 32 + (lk ^ sw) * 8;
        half8 af[8], bf[4];
        // ---- phase 1: A-low quarter + all B, 16 MFMA ----
        #pragma unroll
        for (int mi = 0; mi < 4; mi++)
            af[mi] = *reinterpret_cast<const half8*>(ap + mi * 512);
        #pragma unroll
        for (int ni = 0; ni < 4; ni++)
            bf[ni] = *reinterpret_cast<const half8*>(bp + ni * 512);
        if (st) stageA(kt + 3);        // -> buf (kt-1)&3, fully consumed at kt-1
        __builtin_amdgcn_s_barrier();
        asm volatile("s_waitcnt lgkmcnt(0)" ::: "memory");
        __builtin_amdgcn_sched_barrier(0);             // rule #18: pin MFMA after wait
        __builtin_amdgcn_s_setprio(1);
        #pragma unroll
        for (int mi = 0; mi < 4; mi++)
            #pragma unroll
            for (int ni = 0; ni < 4; ni++)
                acc[mi][ni] = __builtin_amdgcn_mfma_f32_16x16x32_f16(af[mi], bf[ni], acc[mi][ni], 0, 0, 0);
        __builtin_amdgcn_s_setprio(0);
        __builtin_amdgcn_sched_barrier(0);
        __builtin_amdgcn_s_barrier();
        // ---- phase 2: A-high quarter, 16 MFMA ----
        #pragma unroll
        for (int mi = 4; mi < 8; mi++)
            af[mi] = *reinterpret_cast<const half8*>(ap + mi * 512);
        if (st) stageB(kt + 3);
        __builtin_amdgcn_s_barrier();
        asm volatile("s_waitcnt lgkmcnt(0)" ::: "memory");
        __builtin_amdgcn_sched_barrier(0);
        __builtin_amdgcn_s_setprio(1);
        #pragma unroll
        for (int mi = 4; mi < 8; mi++)
            #pragma unroll
            for (int ni = 0; ni < 4; ni++)
                acc[mi][ni] = __builtin_amdgcn_mfma_f32_16x16x32_f16(af[mi], bf[ni], acc[mi][ni], 0, 0, 0);
        __builtin_amdgcn_s_setprio(0);
        __builtin_amdgcn_sched_barrier(0);
    };

    // prologue: fill buffers 0,1,2 (A-before-B per K-tile, order = vmcnt order)
    stageA(0); stageB(0); stageA(1); stageB(1); stageA(2); stageB(2);
    asm volatile("s_waitcnt vmcnt(8)" ::: "memory");   // kt=0's 4 loads landed (per-wave)
    __builtin_amdgcn_s_barrier();                      // -> landed for all waves

    // main loop: NK = 1024/32 = 32 K-tiles; iterations 0..28 stage kt+3
    for (int kt = 0; kt < 29; ++kt) {
        ktile(kt, true);
        asm volatile("s_waitcnt vmcnt(8)" ::: "memory");  // kt+1 landed; kt+2,kt+3 in flight
        __builtin_amdgcn_s_barrier();                     // reads(kt) done before stage(kt+4)
    }
    // epilogue: drain 8 -> 4 -> 0
    ktile(29, false);
    asm volatile("s_waitcnt vmcnt(4)" ::: "memory");      // kt=30 landed
    __builtin_amdgcn_s_barrier();
    ktile(30, false);
    asm volatile("s_waitcnt vmcnt(0)" ::: "memory");      // kt=31 landed
    __builtin_amdgcn_s_barrier();
    ktile(31, false);

    // epilogue: C/D layout col = lane&15 (n), row = (lane>>4)*4 + reg (m)
    #pragma unroll
    for (int mi = 0; mi < 8; mi++) {
        #pragma unroll
        for (int ni = 0; ni < 4; ni++) {
            #pragma unroll
            for (int reg = 0; reg < 4; reg++) {
                int mm = m0 + wm + mi * 16 + (lane >> 4) * 4 + reg;
                int nn = n0 + wn + ni * 16 + (lane & 15);
                float v = acc[mi][ni][reg];
                if (which == 2) v = 1.0f / (1.0f + __expf(-v));
                out[(size_t)mm * Cdim + nn] = (_Float16)v;
            }
        }
    }
}

// ---------------- Kernel 3: chunk-local WKV totals (zero-start) ----------------
__global__ __launch_bounds__(256) void scan_pass1(const _Float16* __restrict__ kb,
                                                  const _Float16* __restrict__ vb,
                                                  const float* __restrict__ tdecay,
                                                  float* __restrict__ tot_a,
                                                  float* __restrict__ tot_b,
                                                  float* __restrict__ tot_p) {
    int idx = blockIdx.x * 256 + threadIdx.x;   // 0 .. NCHUNK*BC-1
    int j = idx >> 13;
    int bc = idx & (BC - 1);
    int b = bc >> 10;
    int c = bc & (Cdim - 1);
    float w = -__expf(tdecay[c]);
    float aa = 0.0f, bb = 0.0f, pp = -1e30f;
    const _Float16* kp = kb + ((size_t)(b * Tdim + j * CHUNK)) * Cdim + c;
    const _Float16* vp = vb + ((size_t)(b * Tdim + j * CHUNK)) * Cdim + c;
    #pragma unroll 4
    for (int t = 0; t < CHUNK; t++) {
        float kt = (float)kp[(size_t)t * Cdim];
        float vt = (float)vp[(size_t)t * Cdim];
        float ww2 = pp + w;
        float p2 = fmaxf(ww2, kt);
        float e1 = __expf(ww2 - p2);
        float e2 = __expf(kt - p2);
        aa = e1 * aa + e2 * vt;
        bb = e1 * bb + e2;
        pp = p2;
    }
    tot_a[idx] = aa; tot_b[idx] = bb; tot_p[idx] = pp;
}

// ---------------- Kernel 4: sequential combine of chunk totals ----------------
__global__ __launch_bounds__(256) void combine_chunks(const float* __restrict__ tot_a,
                                                      const float* __restrict__ tot_b,
                                                      const float* __restrict__ tot_p,
                                                      const float* __restrict__ aa_init,
                                                      const float* __restrict__ bb_init,
                                                      const float* __restrict__ pp_init,
                                                      const float* __restrict__ tdecay,
                                                      float* __restrict__ inc_a,
                                                      float* __restrict__ inc_b,
                                                      float* __restrict__ inc_p) {
    int idx = blockIdx.x * 256 + threadIdx.x;   // 0 .. BC-1
    int c = idx & (Cdim - 1);
    float w = -__expf(tdecay[c]);
    float wL = w * (float)CHUNK;
    float a = aa_init[idx], b = bb_init[idx], p = pp_init[idx];
    for (int j = 0; j < NCHUNK; j++) {
        inc_a[j * BC + idx] = a;
        inc_b[j * BC + idx] = b;
        inc_p[j * BC + idx] = p;
        float ta = tot_a[j * BC + idx];
        float tb = tot_b[j * BC + idx];
        float tp = tot_p[j * BC + idx];
        float px = p + wL;
        float q = fmaxf(px, tp);
        float e1 = __expf(px - q);
        float e2 = __expf(tp - q);
        a = e1 * a + e2 * ta;
        b = e1 * b + e2 * tb;
        p = q;
    }
}

// ---------------- Kernel 5: replay with incoming state ----------------
__global__ __launch_bounds__(256) void scan_pass2(const _Float16* __restrict__ kb,
                                                  const _Float16* __restrict__ vb,
                                                  const _Float16* __restrict__ rb,
                                                  const float* __restrict__ tdecay,
                                                  const float* __restrict__ tfirst,
                                                  const float* __restrict__ inc_a,
                                                  const float* __restrict__ inc_b,
                                                  const float* __restrict__ inc_p,
                                                  float* __restrict__ partial,
                                                  float* __restrict__ ylast) {
    int idx = blockIdx.x * 256 + threadIdx.x;
    int j = idx >> 13;
    int bc = idx & (BC - 1);
    int b = bc >> 10;
    int c = bc & (Cdim - 1);
    float w = -__expf(tdecay[c]);
    float u = tfirst[c];
    float aa = inc_a[idx], bb = inc_b[idx], pp = inc_p[idx];
    const size_t base = ((size_t)(b * Tdim + j * CHUNK)) * Cdim + c;
    const _Float16* kp = kb + base;
    const _Float16* vp = vb + base;
    const _Float16* rp = rb + base;
    float sum = 0.0f, ylv = 0.0f;
    #pragma unroll 4
    for (int t = 0; t < CHUNK; t++) {
        float kt = (float)kp[(size_t)t * Cdim];
        float vt = (float)vp[(size_t)t * Cdim];
        float rt = (float)rp[(size_t)t * Cdim];
        float ww = u + kt;
        float p = fmaxf(pp, ww);
        float e1 = __expf(pp - p);
        float e2 = __expf(ww - p);
        float wkv = (e1 * aa + e2 * vt) / (e1 * bb + e2);
        float y = rt * wkv;
        sum += y;
        ylv = y;
        float ww2 = pp + w;
        float p2 = fmaxf(ww2, kt);
        float e1b = __expf(ww2 - p2);
        float e2b = __expf(kt - p2);
        aa = e1b * aa + e2b * vt;
        bb = e1b * bb + e2b;
        pp = p2;
    }
    partial[idx] = sum;
    if (j == NCHUNK - 1) ylast[bc] = ylv;
}

// ---------------- Kernel 6: z[b,c] = 0.5*(y_last + mean_t y) ----------------
__global__ __launch_bounds__(256) void reduce_z(const float* __restrict__ partial,
                                                const float* __restrict__ ylast,
                                                float* __restrict__ z) {
    int idx = blockIdx.x * 256 + threadIdx.x;   // 0..BC-1
    float s = 0.0f;
    for (int j = 0; j < NCHUNK; j++) s += partial[j * BC + idx];
    z[idx] = 0.5f * (ylast[idx] + s * (1.0f / (float)Tdim));
}

// ---------------- Kernel 7: hx[b,d] = sum_c z[b,c]*Wo[d,c]; write twice ----------------
__global__ __launch_bounds__(256) void final_out(const float* __restrict__ z,
                                                 const float* __restrict__ Wo,
                                                 float* __restrict__ out) {
    int gw = (blockIdx.x * 256 + threadIdx.x) >> 6;   // global wave id, 0..BC-1
    int lane = threadIdx.x & 63;
    int b = gw >> 10;
    int d = gw & (Cdim - 1);
    const float* zr = z + (size_t)b * Cdim;
    const float* wr = Wo + (size_t)d * Cdim;
    float acc = 0.0f;
    #pragma unroll
    for (int i = lane; i < Cdim; i += 64) acc += zr[i] * wr[i];
    #pragma unroll
    for (int off = 32; off > 0; off >>= 1) acc += __shfl_down(acc, off);
    if (lane == 0) {
        out[(size_t)b * Cdim + d] = acc;
        out[(size_t)BC + (size_t)b * Cdim + d] = acc;
    }
}

extern "C" void kernel_launch(void* const* d_in, const int* in_sizes, int n_in,
                              void* d_out, int out_size, void* d_ws, size_t ws_size,
                              hipStream_t stream) {
    const int*   tokens  = (const int*)d_in[0];
    const float* xx_init = (const float*)d_in[1];
    const float* aa_init = (const float*)d_in[2];
    const float* bb_init = (const float*)d_in[3];
    const float* pp_init = (const float*)d_in[4];
    const float* emb     = (const float*)d_in[5];
    const float* tmk     = (const float*)d_in[6];
    const float* tmv     = (const float*)d_in[7];
    const float* tmr     = (const float*)d_in[8];
    const float* tdecay  = (const float*)d_in[9];
    const float* tfirst  = (const float*)d_in[10];
    const float* Wk      = (const float*)d_in[11];
    const float* Wv      = (const float*)d_in[12];
    const float* Wr      = (const float*)d_in[13];
    const float* Wo      = (const float*)d_in[14];
    float* out = (float*)d_out;

    char* ws = (char*)d_ws;
    size_t off = 0;
    auto alloc = [&](size_t bytes) -> void* {
        void* p = ws + off;
        off += (bytes + 255) & ~(size_t)255;
        return p;
    };
    _Float16* xe = (_Float16*)alloc((size_t)Bdim * (Tdim + 1) * Cdim * 2);
    _Float16* xkb = (_Float16*)alloc((size_t)Bdim * Tdim * Cdim * 2);
    _Float16* xvb = (_Float16*)alloc((size_t)Bdim * Tdim * Cdim * 2);
    _Float16* xrb = (_Float16*)alloc((size_t)Bdim * Tdim * Cdim * 2);
    _Float16* kb = xe;   // alias: xe dead after mix3
    _Float16* vb = (_Float16*)alloc((size_t)Bdim * Tdim * Cdim * 2);
    _Float16* rb = (_Float16*)alloc((size_t)Bdim * Tdim * Cdim * 2);
    _Float16* Wh = (_Float16*)alloc((size_t)3 * Cdim * Cdim * 2);
    float* tot_a = (float*)alloc((size_t)NCHUNK * BC * 4);
    float* tot_b = (float*)alloc((size_t)NCHUNK * BC * 4);
    float* tot_p = (float*)alloc((size_t)NCHUNK * BC * 4);
    float* inc_a = (float*)alloc((size_t)NCHUNK * BC * 4);
    float* inc_b = (float*)alloc((size_t)NCHUNK * BC * 4);
    float* inc_p = (float*)alloc((size_t)NCHUNK * BC * 4);
    float* partial = (float*)alloc((size_t)NCHUNK * BC * 4);
    float* ylast   = (float*)alloc((size_t)BC * 4);
    float* zbuf    = (float*)alloc((size_t)BC * 4);

    embed_mix<<<Bdim * (Tdim + 1), 256, 0, stream>>>(tokens, xx_init, emb, xe);
    mix3<<<Bdim * Tdim, 256, 0, stream>>>(xe, tmk, tmv, tmr, xkb, xvb, xrb);
    wconv<<<dim3(1024, 3), 256, 0, stream>>>(Wk, Wv, Wr, Wh);
    gemm_kvr<<<dim3(256, 3), 512, 0, stream>>>(xkb, xvb, xrb, Wh, kb, vb, rb);
    scan_pass1<<<(NCHUNK * BC) / 256, 256, 0, stream>>>(kb, vb, tdecay, tot_a, tot_b, tot_p);
    combine_chunks<<<BC / 256, 256, 0, stream>>>(tot_a, tot_b, tot_p, aa_init, bb_init, pp_init,
                                                 tdecay, inc_a, inc_b, inc_p);
    scan_pass2<<<(NCHUNK * BC) / 256, 256, 0, stream>>>(kb, vb, rb, tdecay, tfirst,
                                                        inc_a, inc_b, inc_p, partial, ylast);
    reduce_z<<<BC / 256, 256, 0, stream>>>(partial, ylast, zbuf);
    final_out<<<(BC / 4), 256, 0, stream>>>(zbuf, Wo, out);
}

// Round 5
// 405.480 us; speedup vs baseline: 1.0333x; 1.0118x over previous
//
#include <hip/hip_runtime.h>

#define Bdim 8
#define Tdim 2048
#define Cdim 1024
#define CHUNK 64
#define NCHUNK 32
#define BC (Bdim*Cdim)

typedef float floatx4 __attribute__((ext_vector_type(4)));
typedef _Float16 half8 __attribute__((ext_vector_type(8)));
typedef _Float16 half4v __attribute__((ext_vector_type(4)));

__device__ __forceinline__ void load16(const void* g, void* l) {
    __builtin_amdgcn_global_load_lds(
        (const __attribute__((address_space(1))) void*)g,
        (__attribute__((address_space(3))) void*)l, 16, 0, 0);
}

// ---------------- Kernel 1: fused embedding gather + time-mix, fp32 -> f16 (x3) ----------------
// Replaces embed_mix + mix3: reads emb rows directly (cur + prev tokens; prev row
// for t=0 is xx_init), mixes in fp32, writes xk/xv/xr in f16.  emb's touched set
// fits L3, so the double gather is L3-served; saves the 34MB xe write + 67MB read.
__global__ __launch_bounds__(256) void fused_mix(const int* __restrict__ tokens,
                                                 const float* __restrict__ xx_init,
                                                 const float* __restrict__ emb,
                                                 const float* __restrict__ tmk,
                                                 const float* __restrict__ tmv,
                                                 const float* __restrict__ tmr,
                                                 _Float16* __restrict__ xk,
                                                 _Float16* __restrict__ xv,
                                                 _Float16* __restrict__ xr) {
    int row = blockIdx.x;              // b*T + t
    int b = row >> 11;
    int t = row & (Tdim - 1);
    const float* cur = emb + (size_t)tokens[row] * Cdim;
    const float* prv = (t == 0) ? (xx_init + (size_t)b * Cdim)
                                : (emb + (size_t)tokens[row - 1] * Cdim);
    int c = threadIdx.x * 4;
    float4 cu = *reinterpret_cast<const float4*>(cur + c);
    float4 pv = *reinterpret_cast<const float4*>(prv + c);
    float4 mk = *reinterpret_cast<const float4*>(tmk + c);
    float4 mv = *reinterpret_cast<const float4*>(tmv + c);
    float4 mr = *reinterpret_cast<const float4*>(tmr + c);
    float cf[4] = {cu.x, cu.y, cu.z, cu.w};
    float pf[4] = {pv.x, pv.y, pv.z, pv.w};
    float mkf[4] = {mk.x, mk.y, mk.z, mk.w};
    float mvf[4] = {mv.x, mv.y, mv.z, mv.w};
    float mrf[4] = {mr.x, mr.y, mr.z, mr.w};
    half4v hk, hv, hr;
    #pragma unroll
    for (int j = 0; j < 4; j++) {
        hk[j] = (_Float16)(mkf[j] * cf[j] + (1.0f - mkf[j]) * pf[j]);
        hv[j] = (_Float16)(mvf[j] * cf[j] + (1.0f - mvf[j]) * pf[j]);
        hr[j] = (_Float16)(mrf[j] * cf[j] + (1.0f - mrf[j]) * pf[j]);
    }
    size_t o = (size_t)row * Cdim + c;
    *reinterpret_cast<half4v*>(xk + o) = hk;
    *reinterpret_cast<half4v*>(xv + o) = hv;
    *reinterpret_cast<half4v*>(xr + o) = hr;
}

// ---------------- Kernel 1c: W fp32 -> f16 ----------------
__global__ __launch_bounds__(256) void wconv(const float* __restrict__ Wk,
                                             const float* __restrict__ Wv,
                                             const float* __restrict__ Wr,
                                             _Float16* __restrict__ Wh) {
    const float* W = blockIdx.y == 0 ? Wk : (blockIdx.y == 1 ? Wv : Wr);
    _Float16* dst = Wh + (size_t)blockIdx.y * Cdim * Cdim;
    int i = (blockIdx.x * 256 + threadIdx.x) * 4;
    float4 f = *reinterpret_cast<const float4*>(W + i);
    half4v h;
    h[0] = (_Float16)f.x; h[1] = (_Float16)f.y; h[2] = (_Float16)f.z; h[3] = (_Float16)f.w;
    *reinterpret_cast<half4v*>(dst + i) = h;
}

// ---------------- Kernel 2: deep-pipelined f16 GEMM (NT), 256x256 tile, BK=32 ----------------
// UNCHANGED from round 4 (control).  out[m,n] = sum_c X[m,c] * W[n,c]; which=2 sigmoid.
__global__ __launch_bounds__(512, 2) void gemm_kvr(const _Float16* __restrict__ xk,
                                                   const _Float16* __restrict__ xv,
                                                   const _Float16* __restrict__ xr,
                                                   const _Float16* __restrict__ Wh,
                                                   _Float16* __restrict__ ko,
                                                   _Float16* __restrict__ vo,
                                                   _Float16* __restrict__ ro) {
    const int which = blockIdx.y;
    const _Float16* X = which == 0 ? xk : (which == 1 ? xv : xr);
    const _Float16* W = Wh + (size_t)which * Cdim * Cdim;
    _Float16* out     = which == 0 ? ko : (which == 1 ? vo : ro);

    const int lin = blockIdx.x;        // 0..255
    const int xcd = lin & 7;
    const int loc = lin >> 3;          // 0..31
    const int mt = xcd * 8 + (loc >> 2);   // 0..63
    const int nt = loc & 3;                // 0..3
    const int m0 = mt * 256;
    const int n0 = nt * 256;

    __shared__ _Float16 As[4 * 8192];
    __shared__ _Float16 Bs[4 * 8192];

    const int tid = threadIdx.x;
    const int lane = tid & 63;
    const int wave = tid >> 6;         // 0..7
    const int wm = (wave >> 2) * 128;  // 2 M-groups
    const int wn = (wave & 3) * 64;    // 4 N-groups
    const int lr = lane & 15;          // fragment row within 16
    const int lk = lane >> 4;          // fragment k-block 0..3
    const int sw = (lr >> 1) & 3;      // row-swizzle, invariant across mi/ni

    const _Float16* Asrc = X + (size_t)m0 * Cdim;
    const _Float16* Bsrc = W + (size_t)n0 * Cdim;

    floatx4 acc[8][4] = {};

    auto stageA = [&](int kt) {
        const int p = kt & 3;
        const int k0 = kt * 32;
        #pragma unroll
        for (int i = 0; i < 2; i++) {
            int e = i * 512 + tid;         // 16B slot index, 0..1023
            int r = e >> 2;                // tile row 0..255
            int cp = e & 3;                // physical colblock
            int cl = cp ^ ((r >> 1) & 3);  // logical (global) colblock
            load16(Asrc + (size_t)r * Cdim + k0 + cl * 8, (char*)(As + p * 8192) + e * 16);
        }
    };
    auto stageB = [&](int kt) {
        const int p = kt & 3;
        const int k0 = kt * 32;
        #pragma unroll
        for (int i = 0; i < 2; i++) {
            int e = i * 512 + tid;
            int r = e >> 2;
            int cp = e & 3;
            int cl = cp ^ ((r >> 1) & 3);
            load16(Bsrc + (size_t)r * Cdim + k0 + cl * 8, (char*)(Bs + p * 8192) + e * 16);
        }
    };

    auto ktile = [&](int kt, bool st) {
        const int p = kt & 3;
        const _Float16* ap = As + p * 8192 + (wm + lr) * 32 + (lk ^ sw) * 8;
        const _Float16* bp = Bs + p * 8192 + (wn + lr) * 32 + (lk ^ sw) * 8;
        half8 af[8], bf[4];
        #pragma unroll
        for (int mi = 0; mi < 4; mi++)
            af[mi] = *reinterpret_cast<const half8*>(ap + mi * 512);
        #pragma unroll
        for (int ni = 0; ni < 4; ni++)
            bf[ni] = *reinterpret_cast<const half8*>(bp + ni * 512);
        if (st) stageA(kt + 3);
        __builtin_amdgcn_s_barrier();
        asm volatile("s_waitcnt lgkmcnt(0)" ::: "memory");
        __builtin_amdgcn_sched_barrier(0);
        __builtin_amdgcn_s_setprio(1);
        #pragma unroll
        for (int mi = 0; mi < 4; mi++)
            #pragma unroll
            for (int ni = 0; ni < 4; ni++)
                acc[mi][ni] = __builtin_amdgcn_mfma_f32_16x16x32_f16(af[mi], bf[ni], acc[mi][ni], 0, 0, 0);
        __builtin_amdgcn_s_setprio(0);
        __builtin_amdgcn_sched_barrier(0);
        __builtin_amdgcn_s_barrier();
        #pragma unroll
        for (int mi = 4; mi < 8; mi++)
            af[mi] = *reinterpret_cast<const half8*>(ap + mi * 512);
        if (st) stageB(kt + 3);
        __builtin_amdgcn_s_barrier();
        asm volatile("s_waitcnt lgkmcnt(0)" ::: "memory");
        __builtin_amdgcn_sched_barrier(0);
        __builtin_amdgcn_s_setprio(1);
        #pragma unroll
        for (int mi = 4; mi < 8; mi++)
            #pragma unroll
            for (int ni = 0; ni < 4; ni++)
                acc[mi][ni] = __builtin_amdgcn_mfma_f32_16x16x32_f16(af[mi], bf[ni], acc[mi][ni], 0, 0, 0);
        __builtin_amdgcn_s_setprio(0);
        __builtin_amdgcn_sched_barrier(0);
    };

    stageA(0); stageB(0); stageA(1); stageB(1); stageA(2); stageB(2);
    asm volatile("s_waitcnt vmcnt(8)" ::: "memory");
    __builtin_amdgcn_s_barrier();

    for (int kt = 0; kt < 29; ++kt) {
        ktile(kt, true);
        asm volatile("s_waitcnt vmcnt(8)" ::: "memory");
        __builtin_amdgcn_s_barrier();
    }
    ktile(29, false);
    asm volatile("s_waitcnt vmcnt(4)" ::: "memory");
    __builtin_amdgcn_s_barrier();
    ktile(30, false);
    asm volatile("s_waitcnt vmcnt(0)" ::: "memory");
    __builtin_amdgcn_s_barrier();
    ktile(31, false);

    #pragma unroll
    for (int mi = 0; mi < 8; mi++) {
        #pragma unroll
        for (int ni = 0; ni < 4; ni++) {
            #pragma unroll
            for (int reg = 0; reg < 4; reg++) {
                int mm = m0 + wm + mi * 16 + (lane >> 4) * 4 + reg;
                int nn = n0 + wn + ni * 16 + (lane & 15);
                float v = acc[mi][ni][reg];
                if (which == 2) v = 1.0f / (1.0f + __expf(-v));
                out[(size_t)mm * Cdim + nn] = (_Float16)v;
            }
        }
    }
}

// ---------------- Kernel 3: chunk-local WKV totals (zero-start), CHUNK=64 ----------------
__global__ __launch_bounds__(256) void scan_pass1(const _Float16* __restrict__ kb,
                                                  const _Float16* __restrict__ vb,
                                                  const float* __restrict__ tdecay,
                                                  float* __restrict__ tot_a,
                                                  float* __restrict__ tot_b,
                                                  float* __restrict__ tot_p) {
    int idx = blockIdx.x * 256 + threadIdx.x;   // 0 .. NCHUNK*BC-1
    int j = idx >> 13;
    int bc = idx & (BC - 1);
    int b = bc >> 10;
    int c = bc & (Cdim - 1);
    float w = -__expf(tdecay[c]);
    float aa = 0.0f, bb = 0.0f, pp = -1e30f;
    const _Float16* kp = kb + ((size_t)(b * Tdim + j * CHUNK)) * Cdim + c;
    const _Float16* vp = vb + ((size_t)(b * Tdim + j * CHUNK)) * Cdim + c;
    #pragma unroll 4
    for (int t = 0; t < CHUNK; t++) {
        float kt = (float)kp[(size_t)t * Cdim];
        float vt = (float)vp[(size_t)t * Cdim];
        float ww2 = pp + w;
        float p2 = fmaxf(ww2, kt);
        float e1 = __expf(ww2 - p2);
        float e2 = __expf(kt - p2);
        aa = e1 * aa + e2 * vt;
        bb = e1 * bb + e2;
        pp = p2;
    }
    tot_a[idx] = aa; tot_b[idx] = bb; tot_p[idx] = pp;
}

// ---------------- Kernel 4: sequential combine of chunk totals ----------------
__global__ __launch_bounds__(256) void combine_chunks(const float* __restrict__ tot_a,
                                                      const float* __restrict__ tot_b,
                                                      const float* __restrict__ tot_p,
                                                      const float* __restrict__ aa_init,
                                                      const float* __restrict__ bb_init,
                                                      const float* __restrict__ pp_init,
                                                      const float* __restrict__ tdecay,
                                                      float* __restrict__ inc_a,
                                                      float* __restrict__ inc_b,
                                                      float* __restrict__ inc_p) {
    int idx = blockIdx.x * 256 + threadIdx.x;   // 0 .. BC-1
    int c = idx & (Cdim - 1);
    float w = -__expf(tdecay[c]);
    float wL = w * (float)CHUNK;
    float a = aa_init[idx], b = bb_init[idx], p = pp_init[idx];
    #pragma unroll 4
    for (int j = 0; j < NCHUNK; j++) {
        inc_a[j * BC + idx] = a;
        inc_b[j * BC + idx] = b;
        inc_p[j * BC + idx] = p;
        float ta = tot_a[j * BC + idx];
        float tb = tot_b[j * BC + idx];
        float tp = tot_p[j * BC + idx];
        float px = p + wL;
        float q = fmaxf(px, tp);
        float e1 = __expf(px - q);
        float e2 = __expf(tp - q);
        a = e1 * a + e2 * ta;
        b = e1 * b + e2 * tb;
        p = q;
    }
}

// ---------------- Kernel 5: replay with incoming state, CHUNK=64 ----------------
__global__ __launch_bounds__(256) void scan_pass2(const _Float16* __restrict__ kb,
                                                  const _Float16* __restrict__ vb,
                                                  const _Float16* __restrict__ rb,
                                                  const float* __restrict__ tdecay,
                                                  const float* __restrict__ tfirst,
                                                  const float* __restrict__ inc_a,
                                                  const float* __restrict__ inc_b,
                                                  const float* __restrict__ inc_p,
                                                  float* __restrict__ partial,
                                                  float* __restrict__ ylast) {
    int idx = blockIdx.x * 256 + threadIdx.x;
    int j = idx >> 13;
    int bc = idx & (BC - 1);
    int b = bc >> 10;
    int c = bc & (Cdim - 1);
    float w = -__expf(tdecay[c]);
    float u = tfirst[c];
    float aa = inc_a[idx], bb = inc_b[idx], pp = inc_p[idx];
    const size_t base = ((size_t)(b * Tdim + j * CHUNK)) * Cdim + c;
    const _Float16* kp = kb + base;
    const _Float16* vp = vb + base;
    const _Float16* rp = rb + base;
    float sum = 0.0f, ylv = 0.0f;
    #pragma unroll 4
    for (int t = 0; t < CHUNK; t++) {
        float kt = (float)kp[(size_t)t * Cdim];
        float vt = (float)vp[(size_t)t * Cdim];
        float rt = (float)rp[(size_t)t * Cdim];
        float ww = u + kt;
        float p = fmaxf(pp, ww);
        float e1 = __expf(pp - p);
        float e2 = __expf(ww - p);
        float wkv = (e1 * aa + e2 * vt) / (e1 * bb + e2);
        float y = rt * wkv;
        sum += y;
        ylv = y;
        float ww2 = pp + w;
        float p2 = fmaxf(ww2, kt);
        float e1b = __expf(ww2 - p2);
        float e2b = __expf(kt - p2);
        aa = e1b * aa + e2b * vt;
        bb = e1b * bb + e2b;
        pp = p2;
    }
    partial[idx] = sum;
    if (j == NCHUNK - 1) ylast[bc] = ylv;
}

// ---------------- Kernel 6: z[b,c] = 0.5*(y_last + mean_t y) ----------------
__global__ __launch_bounds__(256) void reduce_z(const float* __restrict__ partial,
                                                const float* __restrict__ ylast,
                                                float* __restrict__ z) {
    int idx = blockIdx.x * 256 + threadIdx.x;   // 0..BC-1
    float s = 0.0f;
    #pragma unroll 4
    for (int j = 0; j < NCHUNK; j++) s += partial[j * BC + idx];
    z[idx] = 0.5f * (ylast[idx] + s * (1.0f / (float)Tdim));
}

// ---------------- Kernel 7: hx[b,d] = sum_c z[b,c]*Wo[d,c]; write twice ----------------
__global__ __launch_bounds__(256) void final_out(const float* __restrict__ z,
                                                 const float* __restrict__ Wo,
                                                 float* __restrict__ out) {
    int gw = (blockIdx.x * 256 + threadIdx.x) >> 6;   // global wave id, 0..BC-1
    int lane = threadIdx.x & 63;
    int b = gw >> 10;
    int d = gw & (Cdim - 1);
    const float* zr = z + (size_t)b * Cdim;
    const float* wr = Wo + (size_t)d * Cdim;
    float acc = 0.0f;
    #pragma unroll
    for (int i = lane; i < Cdim; i += 64) acc += zr[i] * wr[i];
    #pragma unroll
    for (int off = 32; off > 0; off >>= 1) acc += __shfl_down(acc, off);
    if (lane == 0) {
        out[(size_t)b * Cdim + d] = acc;
        out[(size_t)BC + (size_t)b * Cdim + d] = acc;
    }
}

extern "C" void kernel_launch(void* const* d_in, const int* in_sizes, int n_in,
                              void* d_out, int out_size, void* d_ws, size_t ws_size,
                              hipStream_t stream) {
    const int*   tokens  = (const int*)d_in[0];
    const float* xx_init = (const float*)d_in[1];
    const float* aa_init = (const float*)d_in[2];
    const float* bb_init = (const float*)d_in[3];
    const float* pp_init = (const float*)d_in[4];
    const float* emb     = (const float*)d_in[5];
    const float* tmk     = (const float*)d_in[6];
    const float* tmv     = (const float*)d_in[7];
    const float* tmr     = (const float*)d_in[8];
    const float* tdecay  = (const float*)d_in[9];
    const float* tfirst  = (const float*)d_in[10];
    const float* Wk      = (const float*)d_in[11];
    const float* Wv      = (const float*)d_in[12];
    const float* Wr      = (const float*)d_in[13];
    const float* Wo      = (const float*)d_in[14];
    float* out = (float*)d_out;

    char* ws = (char*)d_ws;
    size_t off = 0;
    auto alloc = [&](size_t bytes) -> void* {
        void* p = ws + off;
        off += (bytes + 255) & ~(size_t)255;
        return p;
    };
    _Float16* xkb = (_Float16*)alloc((size_t)Bdim * Tdim * Cdim * 2);
    _Float16* xvb = (_Float16*)alloc((size_t)Bdim * Tdim * Cdim * 2);
    _Float16* xrb = (_Float16*)alloc((size_t)Bdim * Tdim * Cdim * 2);
    _Float16* kb  = (_Float16*)alloc((size_t)Bdim * Tdim * Cdim * 2);
    _Float16* vb  = (_Float16*)alloc((size_t)Bdim * Tdim * Cdim * 2);
    _Float16* rb  = (_Float16*)alloc((size_t)Bdim * Tdim * Cdim * 2);
    _Float16* Wh = (_Float16*)alloc((size_t)3 * Cdim * Cdim * 2);
    float* tot_a = (float*)alloc((size_t)NCHUNK * BC * 4);
    float* tot_b = (float*)alloc((size_t)NCHUNK * BC * 4);
    float* tot_p = (float*)alloc((size_t)NCHUNK * BC * 4);
    float* inc_a = (float*)alloc((size_t)NCHUNK * BC * 4);
    float* inc_b = (float*)alloc((size_t)NCHUNK * BC * 4);
    float* inc_p = (float*)alloc((size_t)NCHUNK * BC * 4);
    float* partial = (float*)alloc((size_t)NCHUNK * BC * 4);
    float* ylast   = (float*)alloc((size_t)BC * 4);
    float* zbuf    = (float*)alloc((size_t)BC * 4);

    fused_mix<<<Bdim * Tdim, 256, 0, stream>>>(tokens, xx_init, emb, tmk, tmv, tmr,
                                               xkb, xvb, xrb);
    wconv<<<dim3(1024, 3), 256, 0, stream>>>(Wk, Wv, Wr, Wh);
    gemm_kvr<<<dim3(256, 3), 512, 0, stream>>>(xkb, xvb, xrb, Wh, kb, vb, rb);
    scan_pass1<<<(NCHUNK * BC) / 256, 256, 0, stream>>>(kb, vb, tdecay, tot_a, tot_b, tot_p);
    combine_chunks<<<BC / 256, 256, 0, stream>>>(tot_a, tot_b, tot_p, aa_init, bb_init, pp_init,
                                                 tdecay, inc_a, inc_b, inc_p);
    scan_pass2<<<(NCHUNK * BC) / 256, 256, 0, stream>>>(kb, vb, rb, tdecay, tfirst,
                                                        inc_a, inc_b, inc_p, partial, ylast);
    reduce_z<<<BC / 256, 256, 0, stream>>>(partial, ylast, zbuf);
    final_out<<<(BC / 4), 256, 0, stream>>>(zbuf, Wo, out);
}